// Round 8
// baseline (170.310 us; speedup 1.0000x reference)
//
#include <hip/hip_runtime.h>

// SIRD RK4, round 8: single-asm-block packed RK4 step (h=1).
// Evidence R1-R7: lone-wave VALU issue cadence ~4 cyc/inst, independent of
// dep depth; compiler scalarizes swizzled v2f (R4: ~27 scalar insts); per-op
// inline asm adds copies (R5 regression). Fix: ONE asm block per tstep with
// all 15 VOP3P insts, tied "+v" state, "=&v" scratch reused across stages.
//
//   X=(S,I), Y=(u,I), u=c*S-gm;  PK=(S*I, I*u) via v_pk_mul op_sel:[0,1]
//   op_sel_hi:[1,0] (correctness validated in R5).  D recovered per tstep
//   from the RK4-preserved linear invariant D=(mu/gm)*(N-S-I).

typedef float v2f __attribute__((ext_vector_type(2)));

#define N_POP 1.0e7f
#define T_PTS 2048

__global__ __launch_bounds__(64, 1) void sird_kernel(const float* __restrict__ alpha,
                                                     float* __restrict__ out) {
    const int s = blockIdx.x * blockDim.x + threadIdx.x;

    const float beta  = alpha[s * 3 + 0];
    const float gamma = alpha[s * 3 + 1];
    const float mu    = alpha[s * 3 + 2];

    const float c    = beta * (1.0f / N_POP);
    const float gm   = gamma + mu;
    const float hdt  = 0.5f;             // h/2, h = 1
    const float dt   = 1.0f;
    const float w    = 1.0f / 6.0f;
    const float nhc  = -(hdt * c);
    const float ndc  = -(dt * c);
    const float nwc  = -(w * c);
    const float nhcc = nhc * c;
    const float ndcc = ndc * c;
    const float nwcc = nwc * c;
    const float kD   = mu / fmaxf(gm, 1e-30f);
    const float kDN  = kD * (float)N_POP;

    const v2f CH_X = {nhc,  hdt};
    const v2f CD_X = {ndc,  dt};
    const v2f CW_X = {nwc,  w};
    const v2f CH_Y = {nhcc, hdt};
    const v2f CD_Y = {ndcc, dt};
    const v2f CW_Y = {nwcc, w};
    const v2f TWO  = {2.0f, 2.0f};

    const float S0 = N_POP - 1.0f;
    v2f X = {S0, 1.0f};                          // (S, I)
    v2f Y = {__builtin_fmaf(c, S0, -gm), 1.0f};  // (u, I)

    float2* __restrict__ orow = (float2*)out + (size_t)s * T_PTS;
    orow[0] = make_float2(1.0f, 0.0f);

    for (int tstep = 1; tstep < T_PTS; ++tstep) {
        v2f p1, p2, p3, p4, a, b;
        asm(// stage 1
            "v_pk_mul_f32 %[p1], %[X], %[Y] op_sel:[0,1] op_sel_hi:[1,0]\n\t"
            "v_pk_fma_f32 %[a], %[chx], %[p1], %[X] op_sel:[0,0,0] op_sel_hi:[1,1,1]\n\t"
            "v_pk_fma_f32 %[b], %[chy], %[p1], %[Y] op_sel:[0,0,0] op_sel_hi:[1,1,1]\n\t"
            // stage 2
            "v_pk_mul_f32 %[p2], %[a], %[b] op_sel:[0,1] op_sel_hi:[1,0]\n\t"
            "v_pk_fma_f32 %[a], %[chx], %[p2], %[X] op_sel:[0,0,0] op_sel_hi:[1,1,1]\n\t"
            "v_pk_fma_f32 %[b], %[chy], %[p2], %[Y] op_sel:[0,0,0] op_sel_hi:[1,1,1]\n\t"
            // stage 3
            "v_pk_mul_f32 %[p3], %[a], %[b] op_sel:[0,1] op_sel_hi:[1,0]\n\t"
            "v_pk_fma_f32 %[a], %[cdx], %[p3], %[X] op_sel:[0,0,0] op_sel_hi:[1,1,1]\n\t"
            "v_pk_fma_f32 %[b], %[cdy], %[p3], %[Y] op_sel:[0,0,0] op_sel_hi:[1,1,1]\n\t"
            // stage 4
            "v_pk_mul_f32 %[p4], %[a], %[b] op_sel:[0,1] op_sel_hi:[1,0]\n\t"
            // combine: T = (PK1+PK4) + 2*(PK2+PK3)
            "v_pk_add_f32 %[p1], %[p1], %[p4] op_sel:[0,0] op_sel_hi:[1,1]\n\t"
            "v_pk_add_f32 %[p2], %[p2], %[p3] op_sel:[0,0] op_sel_hi:[1,1]\n\t"
            "v_pk_fma_f32 %[p1], %[two], %[p2], %[p1] op_sel:[0,0,0] op_sel_hi:[1,1,1]\n\t"
            "v_pk_fma_f32 %[X], %[cwx], %[p1], %[X] op_sel:[0,0,0] op_sel_hi:[1,1,1]\n\t"
            "v_pk_fma_f32 %[Y], %[cwy], %[p1], %[Y] op_sel:[0,0,0] op_sel_hi:[1,1,1]"
            : [X] "+v"(X), [Y] "+v"(Y),
              [p1] "=&v"(p1), [p2] "=&v"(p2), [p3] "=&v"(p3), [p4] "=&v"(p4),
              [a] "=&v"(a), [b] "=&v"(b)
            : [chx] "v"(CH_X), [chy] "v"(CH_Y),
              [cdx] "v"(CD_X), [cdy] "v"(CD_Y),
              [cwx] "v"(CW_X), [cwy] "v"(CW_Y),
              [two] "v"(TWO));

        const float Dv = __builtin_fmaf(-kD, X.x + X.y, kDN);  // D = kD*(N-S-I)
        orow[tstep] = make_float2(X.y, Dv);
    }
}

extern "C" void kernel_launch(void* const* d_in, const int* in_sizes, int n_in,
                              void* d_out, int out_size, void* d_ws, size_t ws_size,
                              hipStream_t stream) {
    const float* alpha = (const float*)d_in[0];
    float* out = (float*)d_out;
    sird_kernel<<<dim3(T_PTS / 64), dim3(64), 0, stream>>>(alpha, out);
}

// Round 9
// 160.031 us; speedup vs baseline: 1.0642x; 1.0642x over previous
//
#include <hip/hip_runtime.h>

// SIRD RK4, round 9: minimal scalar-inst formulation + unroll-8.
// Measured wall (R1-R8): lone-wave issue cadence ~4 cyc/scalar-VALU-inst,
// independent of dep depth; v_pk_f32 issues at half rate (R8) so packing
// cannot beat scalar. Lever: scalar inst count per tstep.
//
// State (sigma, I) with sigma = c*S  (c = beta/N, gm = gamma+mu):
//   d(sigma) = -c*(sigma*I)         [coef -c*h folds into stage constant]
//   dI       = sigma*I - gm*I = g,  g = fma(-gm, I, m),  m = sigma*I
// Per stage: 4 insts (m, g, 2 updates). Combines: 8 fmas. D from the
// RK4-preserved invariant D = kD*(N - S - I), S = sigma/c:
//   D = fma(-kD/c, sigma, fma(-kD, I, kD*N))  -- 2 fmas, S never formed.
// ~25 insts/tstep; unroll-8 amortizes loop/address to ~0.5 inst/tstep.

#define N_POP 1.0e7f
#define T_PTS 2048

__global__ __launch_bounds__(64, 1) void sird_kernel(const float* __restrict__ alpha,
                                                     float* __restrict__ out) {
    const int s = blockIdx.x * blockDim.x + threadIdx.x;

    const float beta  = alpha[s * 3 + 0];
    const float gamma = alpha[s * 3 + 1];
    const float mu    = alpha[s * 3 + 2];

    const float c    = beta * (1.0f / N_POP);
    const float gm   = gamma + mu;
    const float ngm  = -gm;
    const float h2   = 0.5f;              // h/2, h = 1
    const float nch2 = -0.5f * c;         // -c*h/2   (sigma half-step)
    const float nch  = -c;                // -c*h     (sigma full-step)
    const float w    = 1.0f / 6.0f;
    const float nwc  = -c * (1.0f / 6.0f);
    const float kD   = mu / fmaxf(gm, 1e-30f);
    const float kDN  = kD * (float)N_POP;
    const float nkc  = -kD / c;           // beta > 0 a.s. (uniform*0.5)
    const float nk   = -kD;

    float sg = c * (N_POP - 1.0f);        // sigma = c*S
    float I  = 1.0f;

    float2* __restrict__ orow = (float2*)out + (size_t)s * T_PTS;
    orow[0] = make_float2(1.0f, 0.0f);

#define RK4_STEP(DST)                                                        \
    do {                                                                     \
        const float m1 = sg * I;                                             \
        const float g1 = __builtin_fmaf(ngm, I, m1);                         \
        const float s2 = __builtin_fmaf(nch2, m1, sg);                       \
        const float i2 = __builtin_fmaf(h2, g1, I);                          \
        const float m2 = s2 * i2;                                            \
        const float g2 = __builtin_fmaf(ngm, i2, m2);                        \
        const float s3 = __builtin_fmaf(nch2, m2, sg);                       \
        const float i3 = __builtin_fmaf(h2, g2, I);                          \
        const float m3 = s3 * i3;                                            \
        const float g3 = __builtin_fmaf(ngm, i3, m3);                        \
        const float s4 = __builtin_fmaf(nch, m3, sg);                        \
        const float i4 = I + g3;                                             \
        const float m4 = s4 * i4;                                            \
        const float g4 = __builtin_fmaf(ngm, i4, m4);                        \
        float tm = __builtin_fmaf(2.0f, m2, m1);                             \
        tm = __builtin_fmaf(2.0f, m3, tm);                                   \
        sg = __builtin_fmaf(nwc, m4, __builtin_fmaf(nwc, tm, sg));           \
        float tg = __builtin_fmaf(2.0f, g2, g1);                             \
        tg = __builtin_fmaf(2.0f, g3, tg);                                   \
        I = __builtin_fmaf(w, g4, __builtin_fmaf(w, tg, I));                 \
        const float Dv = __builtin_fmaf(nkc, sg, __builtin_fmaf(nk, I, kDN));\
        (DST) = make_float2(I, Dv);                                          \
    } while (0)

    int tstep = 1;
    // main unrolled-by-8 body: 2047 = 8*255 + 7
    for (; tstep + 7 < T_PTS; tstep += 8) {
        RK4_STEP(orow[tstep + 0]);
        RK4_STEP(orow[tstep + 1]);
        RK4_STEP(orow[tstep + 2]);
        RK4_STEP(orow[tstep + 3]);
        RK4_STEP(orow[tstep + 4]);
        RK4_STEP(orow[tstep + 5]);
        RK4_STEP(orow[tstep + 6]);
        RK4_STEP(orow[tstep + 7]);
    }
    for (; tstep < T_PTS; ++tstep) {
        RK4_STEP(orow[tstep]);
    }
#undef RK4_STEP
}

extern "C" void kernel_launch(void* const* d_in, const int* in_sizes, int n_in,
                              void* d_out, int out_size, void* d_ws, size_t ws_size,
                              hipStream_t stream) {
    const float* alpha = (const float*)d_in[0];
    float* out = (float*)d_out;
    sird_kernel<<<dim3(T_PTS / 64), dim3(64), 0, stream>>>(alpha, out);
}